// Round 4
// baseline (642.261 us; speedup 1.0000x reference)
//
#include <hip/hip_runtime.h>
#include <hip/hip_bf16.h>
#include <stdint.h>

// ---------------------------------------------------------------------------
// InvariantPointAttention, B=1 N=768 CS=384 CZ=128 CH=16 H=12 PQ=4 PV=8
// weight = softmax over size-1 axis == 1.0  =>  _mix(x) == x[:,:,0] (frame 0).
//
// K4 k_attn now: z tile double-buffered in LDS; zb store for tile t+1 runs in
// tile t's softmax slot -> 2 barriers/tile (C,D) instead of 4. Logit-phase
// k/kp loads are bf16 and issued bundled before the bias MFMA (covers L2
// latency). Value phase keeps f32 v/v_pts (no unpack VALU, no MFMA cover).
// ---------------------------------------------------------------------------

typedef float  f32x4 __attribute__((ext_vector_type(4)));
typedef short  s16x8 __attribute__((ext_vector_type(8)));

__device__ __forceinline__ float bf2f(unsigned short u) {
    union { unsigned int i; float f; } v; v.i = ((unsigned int)u) << 16; return v.f;
}
__device__ __forceinline__ unsigned short f2bf(float f) {
    union { float f; unsigned int i; } v; v.f = f;
    unsigned int r = v.i + 0x7fffu + ((v.i >> 16) & 1u);
    return (unsigned short)(r >> 16);
}
__device__ __forceinline__ unsigned packbf2(float a, float b) {
    return (unsigned)f2bf(a) | ((unsigned)f2bf(b) << 16);
}
__device__ __forceinline__ float bval(int c,
    const float* bq, const float* bkv, const float* bqp, const float* bkvp)
{
    if (c < 192)      return bq[c];
    else if (c < 576) return bkv[c - 192];
    else if (c < 720) return bqp[c - 576];
    else              return bkvp[c - 720];
}

// ------------------------------- K0: prep casts ----------------------------
__global__ __launch_bounds__(256) void k_prep(
    const float* __restrict__ s, const float* __restrict__ wexp,
    const float* __restrict__ wq, const float* __restrict__ wkv,
    const float* __restrict__ wqp, const float* __restrict__ wkvp,
    const float* __restrict__ wout,
    const float* __restrict__ bq, const float* __restrict__ bkv,
    const float* __restrict__ bqp, const float* __restrict__ bkvp,
    unsigned short* __restrict__ s_bf, unsigned short* __restrict__ we_bf,
    unsigned short* __restrict__ wc_bf, unsigned short* __restrict__ wo_bf,
    float* __restrict__ bcat)
{
    const int x = blockIdx.x * 256 + threadIdx.x;
    if (x >= 1696896) return;
    if (x < 294912)            s_bf[x] = f2bf(s[x]);
    else if (x < 442368)       we_bf[x - 294912] = f2bf(wexp[x - 294912]);
    else if (x < 516096)       wc_bf[x - 442368] = f2bf(wq[x - 442368]);
    else if (x < 663552)       wc_bf[73728 + (x - 516096)] = f2bf(wkv[x - 516096]);
    else if (x < 718848)       wc_bf[221184 + (x - 663552)] = f2bf(wqp[x - 663552]);
    else if (x < 884736)       wc_bf[276480 + (x - 718848)] = f2bf(wkvp[x - 718848]);
    else if (x < 1695744)      wo_bf[x - 884736] = f2bf(wout[x - 884736]);
    else {
        int j = x - 1695744;   // < 1152
        bcat[j] = bval(j, bq, bkv, bqp, bkvp);
    }
}

// ------------------------------- K1: generic bf16 MFMA GEMM ----------------
// C[m][n] = sum_k A[m][k] * B[n][k]  (+ bias[n]); 64x64 tile, K-chunk 32.
__global__ __launch_bounds__(256) void k_mm(
    const unsigned short* __restrict__ A, int lda,
    const unsigned short* __restrict__ B, int ldb,
    float* __restrict__ C, int ldc, const float* __restrict__ bias,
    int nk, size_t pstride)
{
    const int m0 = blockIdx.x * 64, n0 = blockIdx.y * 64;
    const int koff = blockIdx.z * nk * 32;
    C += (size_t)blockIdx.z * pstride;
    const int t = threadIdx.x;
    const int lane = t & 63, wave = t >> 6, quad = lane >> 4, lcol = lane & 15;
    const int mh = (wave & 1) * 32, nh = (wave >> 1) * 32;
    __shared__ unsigned short As[64 * 40];
    __shared__ unsigned short Bs[64 * 40];
    const int lr = t >> 2, ls = (t & 3) * 8;
    const unsigned short* Ap = A + (size_t)(m0 + lr) * lda + koff + ls;
    const unsigned short* Bp = B + (size_t)(n0 + lr) * ldb + koff + ls;
    f32x4 acc[2][2] = {};

    uint4 av = *(const uint4*)Ap;
    uint4 bv = *(const uint4*)Bp;
    for (int kc = 0; kc < nk; ++kc) {
        __syncthreads();
        *(uint4*)&As[lr * 40 + ls] = av;
        *(uint4*)&Bs[lr * 40 + ls] = bv;
        __syncthreads();
        if (kc + 1 < nk) {
            av = *(const uint4*)(Ap + (size_t)(kc + 1) * 32);
            bv = *(const uint4*)(Bp + (size_t)(kc + 1) * 32);
        }
        s16x8 af0 = *(const s16x8*)&As[(mh + lcol) * 40 + quad * 8];
        s16x8 af1 = *(const s16x8*)&As[(mh + 16 + lcol) * 40 + quad * 8];
        s16x8 bf0 = *(const s16x8*)&Bs[(nh + lcol) * 40 + quad * 8];
        s16x8 bf1 = *(const s16x8*)&Bs[(nh + 16 + lcol) * 40 + quad * 8];
        acc[0][0] = __builtin_amdgcn_mfma_f32_16x16x32_bf16(af0, bf0, acc[0][0], 0, 0, 0);
        acc[0][1] = __builtin_amdgcn_mfma_f32_16x16x32_bf16(af0, bf1, acc[0][1], 0, 0, 0);
        acc[1][0] = __builtin_amdgcn_mfma_f32_16x16x32_bf16(af1, bf0, acc[1][0], 0, 0, 0);
        acc[1][1] = __builtin_amdgcn_mfma_f32_16x16x32_bf16(af1, bf1, acc[1][1], 0, 0, 0);
    }
    #pragma unroll
    for (int r = 0; r < 2; ++r)
        #pragma unroll
        for (int c = 0; c < 2; ++c) {
            int gn = n0 + nh + c * 16 + lcol;
            float bv2 = bias ? bias[gn] : 0.f;
            #pragma unroll
            for (int ii = 0; ii < 4; ++ii) {
                int gm = m0 + mh + r * 16 + quad * 4 + ii;
                C[(size_t)gm * ldc + gn] = acc[r][c][ii] + bv2;
            }
        }
}

// ------------------------------- K2: LayerNorm -> bf16 ---------------------
__global__ __launch_bounds__(256) void k_ln(
    const float* __restrict__ se_raw, const float* __restrict__ ln_g,
    const float* __restrict__ ln_b, unsigned short* __restrict__ se0_bf)
{
    const int n = blockIdx.x * 4 + (threadIdx.x >> 6);
    const int lane = threadIdx.x & 63;
    const float* row = se_raw + (size_t)n * 384;
    float v[6], s1 = 0.f, s2 = 0.f;
    #pragma unroll
    for (int q = 0; q < 6; ++q) {
        v[q] = row[lane + q * 64];
        s1 += v[q]; s2 += v[q] * v[q];
    }
    for (int mk = 1; mk < 64; mk <<= 1) {
        s1 += __shfl_xor(s1, mk, 64);
        s2 += __shfl_xor(s2, mk, 64);
    }
    float mu = s1 * (1.f / 384.f);
    float var = s2 * (1.f / 384.f) - mu * mu;
    float rs = rsqrtf(fmaxf(var, 0.f) + 1e-5f);
    unsigned short* orow = se0_bf + (size_t)n * 384;
    #pragma unroll
    for (int q = 0; q < 6; ++q) {
        int c = lane + q * 64;
        orow[c] = f2bf((v[q] - mu) * rs * ln_g[c] + ln_b[c]);
    }
}

// ------------------------------- K3: post-process --------------------------
// k/kp written bf16 (logit phase unpacks under MFMA cover); v/vp f32.
__global__ __launch_bounds__(256) void k_post(
    const float* __restrict__ lin,
    const float* __restrict__ r_rot, const float* __restrict__ r_trans,
    float* __restrict__ q_out, unsigned short* __restrict__ k_out,
    float* __restrict__ v_out, float* __restrict__ qp_out,
    unsigned short* __restrict__ kp_out, float* __restrict__ vp_out,
    float* __restrict__ k2_out)
{
    const int n0 = blockIdx.x * 8;
    const int t = threadIdx.x;
    __shared__ float kprot[8 * 144];

    for (int r = 0; r < 8; ++r) {
        const int n = n0 + r;
        const float* lrow = lin + (size_t)n * 1152;
        const float* rot = r_rot + (size_t)n * 45;        // frame 0
        for (int u = t; u < 1152; u += 256) {
            if (u < 192) {
                q_out[(size_t)n * 192 + u] = lrow[u];
            } else if (u < 576) {
                int l2 = u - 192, h = l2 >> 5, c = l2 & 31;
                float v = lrow[u];
                if (c < 16) k_out[(size_t)n * 192 + h * 16 + c] = f2bf(v);
                else        v_out[(size_t)n * 192 + h * 16 + (c - 16)] = v;
            } else {
                int y = u - 576;
                int pt = y / 3, i = y - pt * 3;
                float t0 = r_trans[(size_t)n * 15 + i];
                float v;
                if (pt < 48) {
                    v = rot[i*3+0] * lrow[576 + pt]
                      + rot[i*3+1] * lrow[576 + 48 + pt]
                      + rot[i*3+2] * lrow[576 + 96 + pt] + t0;
                    qp_out[(size_t)n * 144 + pt * 3 + i] = v;
                } else {
                    int pp = pt - 48;
                    v = rot[i*3+0] * lrow[720 + pp]
                      + rot[i*3+1] * lrow[720 + 144 + pp]
                      + rot[i*3+2] * lrow[720 + 288 + pp] + t0;
                    int h = pp / 12, pl = pp - h * 12;
                    if (pl < 4) {
                        kp_out[(size_t)n * 144 + (h * 4 + pl) * 3 + i] = f2bf(v);
                        kprot[r * 144 + (h * 4 + pl) * 3 + i] = v;
                    } else {
                        vp_out[(size_t)n * 288 + (h * 8 + (pl - 4)) * 3 + i] = v;
                    }
                }
            }
        }
    }
    __syncthreads();
    if (t < 96) {
        int r = t / 12, h = t - r * 12;
        float ss = 0.f;
        #pragma unroll
        for (int d = 0; d < 12; ++d) {
            float v = kprot[r * 144 + h * 12 + d];
            ss += v * v;
        }
        k2_out[(size_t)(n0 + r) * 12 + h] = ss;
    }
}

// ------------------------------- K4: fused attention -----------------------
__global__ __launch_bounds__(256, 3) void k_attn(
    const float* __restrict__ z, const float* __restrict__ mask,
    const float* __restrict__ head_w, const float* __restrict__ wb,
    const float* __restrict__ bb,
    const float* __restrict__ r_rot, const float* __restrict__ r_trans,
    const float* __restrict__ q_ws, const float* __restrict__ qp_ws,
    const float* __restrict__ k2_ws,
    const unsigned short* __restrict__ k_bf, const float* __restrict__ v_f,
    const unsigned short* __restrict__ kp_bf, const float* __restrict__ vp_f,
    unsigned short* __restrict__ cat)
{
    const int i = blockIdx.x;
    const int t = threadIdx.x;
    const int lane = t & 63, wv = t >> 6;
    const int quad = lane >> 4, lcol = lane & 15;

    __shared__ short zb[2][64 * 136];          // double-buffered z tile (34.8 KB)
    __shared__ float L[64 * 17];               // logits [jl][h]; reused as vbuf
    __shared__ float Pt[16 * 68];              // softmax weights [h][jl]
    __shared__ float qs[192], qps[144];
    __shared__ float ulra[768];
    __shared__ float m_s[16], l_s[16], alph_s[16], linv_s[16];
    __shared__ float optb[288];

    const float c_qk = 0.14433756729740643f;   // 1/sqrt(3*CH)
    const float c_b  = 0.57735026918962576f;   // 1/sqrt(3)

    if (t < 192) qs[t]  = q_ws[(size_t)i * 192 + t];
    if (t < 144) qps[t] = qp_ws[(size_t)i * 144 + t];
    if (t >= 192 && t < 208) { int u = t - 192; m_s[u] = -1e30f; l_s[u] = 0.f; alph_s[u] = 1.f; }
    for (int x = t; x < 768; x += 256) ulra[x] = mask[(size_t)x * 5];
    for (int x = t; x < 4 * 68; x += 256) Pt[12 * 68 + x] = 0.f;   // pad heads
    const float ulr_i = mask[(size_t)i * 5];

    // wb B-fragments, resident in registers
    s16x8 wbf[4];
    #pragma unroll
    for (int kb = 0; kb < 4; ++kb) {
        #pragma unroll
        for (int j = 0; j < 8; ++j) {
            int c = kb * 32 + quad * 8 + j;
            wbf[kb][j] = (lcol < 12) ? (short)f2bf(wb[(size_t)lcol * 128 + c]) : (short)0;
        }
    }

    // per-thread hoisted q/qp/consts for the logit phase (head = lcol, clamped)
    const int hh = (lcol < 12) ? lcol : 11;
    f32x4 qv[4], qpv[3];
    float q2_r = 0.f;
    {
        const float* qg  = q_ws  + (size_t)i * 192 + hh * 16;
        const float* qpg = qp_ws + (size_t)i * 144 + hh * 12;
        #pragma unroll
        for (int m = 0; m < 4; ++m) qv[m] = *(const f32x4*)(qg + m * 4);
        #pragma unroll
        for (int m = 0; m < 3; ++m) {
            qpv[m] = *(const f32x4*)(qpg + m * 4);
            #pragma unroll
            for (int e = 0; e < 4; ++e) q2_r += qpv[m][e] * qpv[m][e];
        }
    }
    float xh = head_w[hh];
    const float cpt_r = -0.5f * logf(1.f + __expf(xh)) * 0.13608276348795434f;
    const float cbb_r = c_b * bb[hh];

    f32x4 acc_op[2] = { {0.f,0.f,0.f,0.f}, {0.f,0.f,0.f,0.f} };  // o_pair (MFMA C)
    f32x4 acc_s = {0.f,0.f,0.f,0.f};                              // o / o_pt partial

    // value-phase roles: 240 threads x 32 j (two halves)
    int vu = -1, vhalf = 0;
    if (t < 120) { vu = t; vhalf = 0; }
    else if (t >= 128 && t < 248) { vu = t - 128; vhalf = 1; }
    int vrole = -1; const float* vsrc = nullptr; int vstride = 0, voff = 0;
    if (vu >= 0) {
        if (vu < 48) { vrole = vu >> 2;       vsrc = v_f;  vstride = 192; voff = vu * 4; }
        else         { vrole = (vu - 48) / 6; vsrc = vp_f; vstride = 288; voff = (vu - 48) * 4; }
    }

    const int jlb = wv * 16 + quad * 4;
    const int zrow = wv * 16 + lcol;
    const int sigm = (zrow >> 3) & 3;

    // prologue: load z tile 0, store zb[0], issue z tile 1, one barrier
    const float* zbase = z + (size_t)i * 98304;
    f32x4 zr[8];
    #pragma unroll
    for (int sx = 0; sx < 8; ++sx)
        zr[sx] = *(const f32x4*)(zbase + (size_t)(t + sx * 256) * 4);
    #pragma unroll
    for (int sx = 0; sx < 8; ++sx) {
        int idx = t + sx * 256;
        int jl = idx >> 5, cq = idx & 31;
        int ch = (cq >> 1) ^ ((jl >> 3) & 3);
        uint2 pk;
        pk.x = packbf2(zr[sx][0], zr[sx][1]);
        pk.y = packbf2(zr[sx][2], zr[sx][3]);
        *(uint2*)&zb[0][jl * 136 + ch * 8 + (cq & 1) * 4] = pk;
    }
    #pragma unroll
    for (int sx = 0; sx < 8; ++sx)
        zr[sx] = *(const f32x4*)(zbase + 8192 + (size_t)(t + sx * 256) * 4);
    __syncthreads();

    int cur = 0;
    for (int tt = 0; tt < 12; ++tt) {
        const int j0 = tt * 64;

        // ---- issue k/kp/K2 bundled loads for this thread's 4 j-rows ----
        uint4 ka[4], kb4[4]; uint2 p0[4], p1[4], p2[4]; float K2r[4];
        #pragma unroll
        for (int r = 0; r < 4; ++r) {
            int jr = j0 + jlb + r;
            const unsigned short* kr = k_bf + (size_t)jr * 192 + hh * 16;
            ka[r]  = *(const uint4*)kr;
            kb4[r] = *(const uint4*)(kr + 8);
            const unsigned short* pr = kp_bf + (size_t)jr * 144 + hh * 12;
            p0[r] = *(const uint2*)pr;
            p1[r] = *(const uint2*)(pr + 4);
            p2[r] = *(const uint2*)(pr + 8);
            K2r[r] = k2_ws[(size_t)jr * 12 + hh];
        }

        // ---- bias via MFMA (covers the L2 latency of the loads above) ----
        f32x4 d = {0.f, 0.f, 0.f, 0.f};
        #pragma unroll
        for (int kb = 0; kb < 4; ++kb) {
            s16x8 a = *(const s16x8*)&zb[cur][zrow * 136 + ((kb * 4 + quad) ^ sigm) * 8];
            d = __builtin_amdgcn_mfma_f32_16x16x32_bf16(a, wbf[kb], d, 0, 0, 0);
        }

        // ---- logits: thread owns (jl = jlb+r, h = lcol) ----
        if (lcol < 12) {
            #pragma unroll
            for (int r = 0; r < 4; ++r) {
                int jl = jlb + r;
                const unsigned* kwa = (const unsigned*)&ka[r];
                const unsigned* kwb = (const unsigned*)&kb4[r];
                float qk = 0.f;
                #pragma unroll
                for (int m = 0; m < 4; ++m) {
                    qk += qv[m >> 1][(m & 1) * 2 + 0] * bf2f((unsigned short)(kwa[m] & 0xffffu));
                    qk += qv[m >> 1][(m & 1) * 2 + 1] * bf2f((unsigned short)(kwa[m] >> 16));
                }
                #pragma unroll
                for (int m = 0; m < 4; ++m) {
                    qk += qv[2 + (m >> 1)][(m & 1) * 2 + 0] * bf2f((unsigned short)(kwb[m] & 0xffffu));
                    qk += qv[2 + (m >> 1)][(m & 1) * 2 + 1] * bf2f((unsigned short)(kwb[m] >> 16));
                }
                float dp = 0.f;
                dp += qpv[0][0] * bf2f((unsigned short)(p0[r].x & 0xffffu));
                dp += qpv[0][1] * bf2f((unsigned short)(p0[r].x >> 16));
                dp += qpv[0][2] * bf2f((unsigned short)(p0[r].y & 0xffffu));
                dp += qpv[0][3] * bf2f((unsigned short)(p0[r].y >> 16));
                dp += qpv[1][0] * bf2f((unsigned short)(p1[r].x & 0xffffu));
                dp += qpv[1][1] * bf2f((unsigned short)(p1[r].x >> 16));
                dp += qpv[1][2] * bf2f((unsigned short)(p1[r].y & 0xffffu));
                dp += qpv[1][3] * bf2f((unsigned short)(p1[r].y >> 16));
                dp += qpv[2][0] * bf2f((unsigned short)(p2[r].x & 0xffffu));
                dp += qpv[2][1] * bf2f((unsigned short)(p2[r].x >> 16));
                dp += qpv[2][2] * bf2f((unsigned short)(p2[r].y & 0xffffu));
                dp += qpv[2][3] * bf2f((unsigned short)(p2[r].y >> 16));
                float ptt = cpt_r * (q2_r + K2r[r] - 2.f * dp);
                float lg = c_qk * qk + ptt + 1e5f * (ulr_i * ulra[j0 + jl] - 1.f)
                         + c_b * d[r] + cbb_r;
                L[jl * 17 + lcol] = lg;
            }
        }
        __syncthreads();   // C: L complete; prev-tile zb/Pt readers done

        // ---- online softmax update (16 lanes per head) ----
        if (t < 192) {
            int h = t >> 4, u = t & 15;
            float v0 = L[(u * 4 + 0) * 17 + h];
            float v1 = L[(u * 4 + 1) * 17 + h];
            float v2 = L[(u * 4 + 2) * 17 + h];
            float v3 = L[(u * 4 + 3) * 17 + h];
            float mx = fmaxf(fmaxf(v0, v1), fmaxf(v2, v3));
            for (int mk = 1; mk < 16; mk <<= 1) mx = fmaxf(mx, __shfl_xor(mx, mk, 16));
            float mold = m_s[h];
            float mnew = fmaxf(mold, mx);
            float w0 = __expf(v0 - mnew), w1 = __expf(v1 - mnew);
            float w2 = __expf(v2 - mnew), w3 = __expf(v3 - mnew);
            Pt[h * 68 + u * 4 + 0] = w0;
            Pt[h * 68 + u * 4 + 1] = w1;
            Pt[h * 68 + u * 4 + 2] = w2;
            Pt[h * 68 + u * 4 + 3] = w3;
            float sm = w0 + w1 + w2 + w3;
            for (int mk = 1; mk < 16; mk <<= 1) sm += __shfl_xor(sm, mk, 16);
            if (u == 0) {
                float al = __expf(mold - mnew);
                m_s[h] = mnew; alph_s[h] = al;
                l_s[h] = l_s[h] * al + sm;
            }
        }
        // ---- overlapped with softmax: store next z tile, reissue prefetch ----
        if (tt < 11) {
            #pragma unroll
            for (int sx = 0; sx < 8; ++sx) {
                int idx = t + sx * 256;
                int jl = idx >> 5, cq = idx & 31;
                int ch = (cq >> 1) ^ ((jl >> 3) & 3);
                uint2 pk;
                pk.x = packbf2(zr[sx][0], zr[sx][1]);
                pk.y = packbf2(zr[sx][2], zr[sx][3]);
                *(uint2*)&zb[cur ^ 1][jl * 136 + ch * 8 + (cq & 1) * 4] = pk;
            }
            if (tt < 10) {
                const float* znext = zbase + (size_t)(tt + 2) * 8192;
                #pragma unroll
                for (int sx = 0; sx < 8; ++sx)
                    zr[sx] = *(const f32x4*)(znext + (size_t)(t + sx * 256) * 4);
            }
        }
        __syncthreads();   // D: Pt/alph ready; zb[cur^1] stored

        // ---- o_pair MFMA: D[h][c] += P(16x64) @ z(64x128) ----
        {
            float al[4];
            #pragma unroll
            for (int r = 0; r < 4; ++r) al[r] = alph_s[quad * 4 + r];
            #pragma unroll
            for (int nt = 0; nt < 2; ++nt)
                #pragma unroll
                for (int r = 0; r < 4; ++r) acc_op[nt][r] *= al[r];
            #pragma unroll
            for (int kb = 0; kb < 2; ++kb) {
                f32x4 pa = *(const f32x4*)&Pt[lcol * 68 + kb * 32 + quad * 8];
                f32x4 pb = *(const f32x4*)&Pt[lcol * 68 + kb * 32 + quad * 8 + 4];
                union { s16x8 v; unsigned u[4]; } af;
                af.u[0] = packbf2(pa[0], pa[1]);
                af.u[1] = packbf2(pa[2], pa[3]);
                af.u[2] = packbf2(pb[0], pb[1]);
                af.u[3] = packbf2(pb[2], pb[3]);
                #pragma unroll
                for (int nt = 0; nt < 2; ++nt) {
                    int c = wv * 32 + nt * 16 + lcol;
                    int csw = ((c >> 3) ^ quad) * 8 + (c & 7);
                    s16x8 bfg;
                    #pragma unroll
                    for (int j = 0; j < 8; ++j)
                        bfg[j] = zb[cur][(kb * 32 + quad * 8 + j) * 136 + csw];
                    acc_op[nt] = __builtin_amdgcn_mfma_f32_16x16x32_bf16(af.v, bfg, acc_op[nt], 0, 0, 0);
                }
            }
        }
        // ---- scalar o / o_pt (f32 v, v_pts from L2: no unpack VALU) ----
        if (vu >= 0) {
            float alpha = alph_s[vrole];
            f32x4 a = acc_s;
            a[0] *= alpha; a[1] *= alpha; a[2] *= alpha; a[3] *= alpha;
            const float* prow = &Pt[vrole * 68 + vhalf * 32];
            const float* src = vsrc + (size_t)(j0 + vhalf * 32) * vstride + voff;
            #pragma unroll 4
            for (int jj = 0; jj < 32; jj += 4) {
                f32x4 p = *(const f32x4*)(prow + jj);
                #pragma unroll
                for (int m = 0; m < 4; ++m) {
                    f32x4 w = *(const f32x4*)(src + (size_t)(jj + m) * vstride);
                    float pm = p[m];
                    a[0] += pm * w[0];
                    a[1] += pm * w[1];
                    a[2] += pm * w[2];
                    a[3] += pm * w[3];
                }
            }
            acc_s = a;
        }
        if (tt < 11) cur ^= 1;
    }

    // ------------------------------ epilogue -------------------------------
    __syncthreads();
    if (t < 16) linv_s[t] = (t < 12) ? 1.f / l_s[t] : 0.f;
    float* vbuf = L;    // safe: no more L readers
    if (vu >= 0) {
        #pragma unroll
        for (int m = 0; m < 4; ++m) vbuf[(vu * 2 + vhalf) * 4 + m] = acc_s[m];
    }
    __syncthreads();
    unsigned short* crow = cat + (size_t)i * 2112;
    if (t < 120) {   // combine value halves
        int role = (t < 48) ? (t >> 2) : (t - 48) / 6;
        float li = linv_s[role];
        float f[4];
        #pragma unroll
        for (int m = 0; m < 4; ++m)
            f[m] = (vbuf[(t * 2) * 4 + m] + vbuf[(t * 2 + 1) * 4 + m]) * li;
        if (t < 48) {
            #pragma unroll
            for (int m = 0; m < 4; ++m) crow[t * 4 + m] = f2bf(f[m]);
        } else {
            int e0 = (t - 48) * 4;
            optb[e0 + 0] = f[0]; optb[e0 + 1] = f[1];
            optb[e0 + 2] = f[2]; optb[e0 + 3] = f[3];
        }
    }
    {
        #pragma unroll
        for (int nt = 0; nt < 2; ++nt)
            #pragma unroll
            for (int r = 0; r < 4; ++r) {
                int h = quad * 4 + r;
                if (h < 12)
                    crow[576 + h * 128 + wv * 32 + nt * 16 + lcol] = f2bf(acc_op[nt][r] * linv_s[h]);
            }
    }
    __syncthreads();
    if (t < 96) {   // invert frame 0, write o_pt xyz + norm
        int hp = t;
        const float* rot = r_rot + (size_t)i * 45;
        float d0 = optb[hp * 3 + 0] - r_trans[(size_t)i * 15 + 0];
        float d1 = optb[hp * 3 + 1] - r_trans[(size_t)i * 15 + 1];
        float d2 = optb[hp * 3 + 2] - r_trans[(size_t)i * 15 + 2];
        float f0 = rot[0] * d0 + rot[3] * d1 + rot[6] * d2;
        float f1 = rot[1] * d0 + rot[4] * d1 + rot[7] * d2;
        float f2 = rot[2] * d0 + rot[5] * d1 + rot[8] * d2;
        crow[192 + hp] = f2bf(f0);
        crow[288 + hp] = f2bf(f1);
        crow[384 + hp] = f2bf(f2);
        crow[480 + hp] = f2bf(sqrtf(f0 * f0 + f1 * f1 + f2 * f2 + 1e-8f));
    }
}

// ------------------------------- K5: reduce split-K parts + bias -----------
__global__ __launch_bounds__(256) void k_out_red(
    const float* __restrict__ parts, const float* __restrict__ bout,
    float* __restrict__ out)
{
    const int x = blockIdx.x * 256 + threadIdx.x;   // < 294912
    float s = bout[x % 384];
    #pragma unroll
    for (int p = 0; p < 6; ++p) s += parts[(size_t)p * 294912 + x];
    out[x] = s;
}

// ------------------------------- launch ------------------------------------
extern "C" void kernel_launch(void* const* d_in, const int* in_sizes, int n_in,
                              void* d_out, int out_size, void* d_ws, size_t ws_size,
                              hipStream_t stream)
{
    const float* s       = (const float*)d_in[0];
    const float* z       = (const float*)d_in[1];
    const float* r_rot   = (const float*)d_in[2];
    const float* r_trans = (const float*)d_in[3];
    const float* mask    = (const float*)d_in[4];
    const float* wq      = (const float*)d_in[5];
    const float* bq      = (const float*)d_in[6];
    const float* wkv     = (const float*)d_in[7];
    const float* bkv     = (const float*)d_in[8];
    const float* wqp     = (const float*)d_in[9];
    const float* bqp     = (const float*)d_in[10];
    const float* wkvp    = (const float*)d_in[11];
    const float* bkvp    = (const float*)d_in[12];
    const float* wb      = (const float*)d_in[13];
    const float* bb      = (const float*)d_in[14];
    const float* head_w  = (const float*)d_in[15];
    const float* wout    = (const float*)d_in[16];
    const float* bout    = (const float*)d_in[17];
    const float* wexp    = (const float*)d_in[18];
    const float* bexp    = (const float*)d_in[19];
    const float* ln_g    = (const float*)d_in[20];
    const float* ln_b    = (const float*)d_in[21];
    // d_in[22]=ww, d_in[23]=bw unused: softmax over size-1 axis == 1.0

    float* wsf = (float*)d_ws;
    float* se_raw = wsf;                  // 294912
    float* lin    = wsf + 294912;         // 884736
    float* qf     = wsf + 1179648;        // 147456
    float* qpf    = wsf + 1327104;        // 110592
    float* k2w    = wsf + 1437696;        // 9216
    float* bcat   = wsf + 1446912;        // 1152
    float* parts  = wsf + 1448064;        // 1769472 (6 x 294912)
    float* vf     = wsf + 3217536;        // 147456
    float* vpf    = wsf + 3364992;        // 221184
    unsigned short* ub = (unsigned short*)(wsf + 3586176);
    unsigned short* s_bf   = ub;              // 294912
    unsigned short* we_bf  = ub + 294912;     // 147456
    unsigned short* wc_bf  = ub + 442368;     // 442368
    unsigned short* wo_bf  = ub + 884736;     // 811008
    unsigned short* se0_bf = ub + 1695744;    // 294912
    unsigned short* kbf    = ub + 1990656;    // 147456
    unsigned short* kpbf   = ub + 2138112;    // 110592
    unsigned short* cat_bf = ub + 2248704;    // 1622016
    float* out = (float*)d_out;

    k_prep<<<6629, 256, 0, stream>>>(s, wexp, wq, wkv, wqp, wkvp, wout,
                                     bq, bkv, bqp, bkvp,
                                     s_bf, we_bf, wc_bf, wo_bf, bcat);
    k_mm<<<dim3(12, 6, 1), 256, 0, stream>>>(s_bf, 384, we_bf, 384,
                                             se_raw, 384, bexp, 12, 0);
    k_ln<<<192, 256, 0, stream>>>(se_raw, ln_g, ln_b, se0_bf);
    k_mm<<<dim3(12, 18, 1), 256, 0, stream>>>(se0_bf, 384, wc_bf, 384,
                                              lin, 1152, bcat, 12, 0);
    k_post<<<96, 256, 0, stream>>>(lin, r_rot, r_trans,
                                   qf, kbf, vf, qpf, kpbf, vpf, k2w);
    k_attn<<<768, 256, 0, stream>>>(z, mask, head_w, wb, bb, r_rot, r_trans,
                                    qf, qpf, k2w, kbf, vf, kpbf, vpf, cat_bf);
    k_mm<<<dim3(12, 6, 6), 256, 0, stream>>>(cat_bf, 2112, wo_bf, 2112,
                                             parts, 384, nullptr, 11, 294912);
    k_out_red<<<1152, 256, 0, stream>>>(parts, bout, out);
}

// Round 5
// 559.586 us; speedup vs baseline: 1.1477x; 1.1477x over previous
//
#include <hip/hip_runtime.h>
#include <hip/hip_bf16.h>
#include <stdint.h>

// ---------------------------------------------------------------------------
// InvariantPointAttention, B=1 N=768 CS=384 CZ=128 CH=16 H=12 PQ=4 PV=8
// weight = softmax over size-1 axis == 1.0  =>  _mix(x) == x[:,:,0] (frame 0).
//
// K4 k_attn: round-0 proven schedule (4 barriers/tile, single zb, bundled bf16
// k/kp loads hidden under bias MFMA), but SPLIT-KV: each block does half the
// j-range (6 tiles), grid 1536, online-softmax partials to workspace.
// LDS ~29 KB -> 5 blocks/CU (vs 3 grid-limited before).
// K6 k_merge: combine the two halves per row, frame-0 inversion, write cat.
// ---------------------------------------------------------------------------

typedef float  f32x4 __attribute__((ext_vector_type(4)));
typedef short  s16x8 __attribute__((ext_vector_type(8)));

__device__ __forceinline__ float bf2f(unsigned short u) {
    union { unsigned int i; float f; } v; v.i = ((unsigned int)u) << 16; return v.f;
}
__device__ __forceinline__ unsigned short f2bf(float f) {
    union { float f; unsigned int i; } v; v.f = f;
    unsigned int r = v.i + 0x7fffu + ((v.i >> 16) & 1u);
    return (unsigned short)(r >> 16);
}
__device__ __forceinline__ unsigned packbf2(float a, float b) {
    return (unsigned)f2bf(a) | ((unsigned)f2bf(b) << 16);
}
__device__ __forceinline__ float bval(int c,
    const float* bq, const float* bkv, const float* bqp, const float* bkvp)
{
    if (c < 192)      return bq[c];
    else if (c < 576) return bkv[c - 192];
    else if (c < 720) return bqp[c - 576];
    else              return bkvp[c - 720];
}

// ------------------------------- K0: prep casts ----------------------------
__global__ __launch_bounds__(256) void k_prep(
    const float* __restrict__ s, const float* __restrict__ wexp,
    const float* __restrict__ wq, const float* __restrict__ wkv,
    const float* __restrict__ wqp, const float* __restrict__ wkvp,
    const float* __restrict__ wout,
    const float* __restrict__ bq, const float* __restrict__ bkv,
    const float* __restrict__ bqp, const float* __restrict__ bkvp,
    unsigned short* __restrict__ s_bf, unsigned short* __restrict__ we_bf,
    unsigned short* __restrict__ wc_bf, unsigned short* __restrict__ wo_bf,
    float* __restrict__ bcat)
{
    const int x = blockIdx.x * 256 + threadIdx.x;
    if (x >= 1696896) return;
    if (x < 294912)            s_bf[x] = f2bf(s[x]);
    else if (x < 442368)       we_bf[x - 294912] = f2bf(wexp[x - 294912]);
    else if (x < 516096)       wc_bf[x - 442368] = f2bf(wq[x - 442368]);
    else if (x < 663552)       wc_bf[73728 + (x - 516096)] = f2bf(wkv[x - 516096]);
    else if (x < 718848)       wc_bf[221184 + (x - 663552)] = f2bf(wqp[x - 663552]);
    else if (x < 884736)       wc_bf[276480 + (x - 718848)] = f2bf(wkvp[x - 718848]);
    else if (x < 1695744)      wo_bf[x - 884736] = f2bf(wout[x - 884736]);
    else {
        int j = x - 1695744;   // < 1152
        bcat[j] = bval(j, bq, bkv, bqp, bkvp);
    }
}

// ------------------------------- K1: generic bf16 MFMA GEMM ----------------
// C[m][n] = sum_k A[m][k] * B[n][k]  (+ bias[n]); 64x64 tile, K-chunk 32.
__global__ __launch_bounds__(256) void k_mm(
    const unsigned short* __restrict__ A, int lda,
    const unsigned short* __restrict__ B, int ldb,
    float* __restrict__ C, int ldc, const float* __restrict__ bias,
    int nk, size_t pstride)
{
    const int m0 = blockIdx.x * 64, n0 = blockIdx.y * 64;
    const int koff = blockIdx.z * nk * 32;
    C += (size_t)blockIdx.z * pstride;
    const int t = threadIdx.x;
    const int lane = t & 63, wave = t >> 6, quad = lane >> 4, lcol = lane & 15;
    const int mh = (wave & 1) * 32, nh = (wave >> 1) * 32;
    __shared__ unsigned short As[64 * 40];
    __shared__ unsigned short Bs[64 * 40];
    const int lr = t >> 2, ls = (t & 3) * 8;
    const unsigned short* Ap = A + (size_t)(m0 + lr) * lda + koff + ls;
    const unsigned short* Bp = B + (size_t)(n0 + lr) * ldb + koff + ls;
    f32x4 acc[2][2] = {};

    uint4 av = *(const uint4*)Ap;
    uint4 bv = *(const uint4*)Bp;
    for (int kc = 0; kc < nk; ++kc) {
        __syncthreads();
        *(uint4*)&As[lr * 40 + ls] = av;
        *(uint4*)&Bs[lr * 40 + ls] = bv;
        __syncthreads();
        if (kc + 1 < nk) {
            av = *(const uint4*)(Ap + (size_t)(kc + 1) * 32);
            bv = *(const uint4*)(Bp + (size_t)(kc + 1) * 32);
        }
        s16x8 af0 = *(const s16x8*)&As[(mh + lcol) * 40 + quad * 8];
        s16x8 af1 = *(const s16x8*)&As[(mh + 16 + lcol) * 40 + quad * 8];
        s16x8 bf0 = *(const s16x8*)&Bs[(nh + lcol) * 40 + quad * 8];
        s16x8 bf1 = *(const s16x8*)&Bs[(nh + 16 + lcol) * 40 + quad * 8];
        acc[0][0] = __builtin_amdgcn_mfma_f32_16x16x32_bf16(af0, bf0, acc[0][0], 0, 0, 0);
        acc[0][1] = __builtin_amdgcn_mfma_f32_16x16x32_bf16(af0, bf1, acc[0][1], 0, 0, 0);
        acc[1][0] = __builtin_amdgcn_mfma_f32_16x16x32_bf16(af1, bf0, acc[1][0], 0, 0, 0);
        acc[1][1] = __builtin_amdgcn_mfma_f32_16x16x32_bf16(af1, bf1, acc[1][1], 0, 0, 0);
    }
    #pragma unroll
    for (int r = 0; r < 2; ++r)
        #pragma unroll
        for (int c = 0; c < 2; ++c) {
            int gn = n0 + nh + c * 16 + lcol;
            float bv2 = bias ? bias[gn] : 0.f;
            #pragma unroll
            for (int ii = 0; ii < 4; ++ii) {
                int gm = m0 + mh + r * 16 + quad * 4 + ii;
                C[(size_t)gm * ldc + gn] = acc[r][c][ii] + bv2;
            }
        }
}

// ------------------------------- K2: LayerNorm -> bf16 ---------------------
__global__ __launch_bounds__(256) void k_ln(
    const float* __restrict__ se_raw, const float* __restrict__ ln_g,
    const float* __restrict__ ln_b, unsigned short* __restrict__ se0_bf)
{
    const int n = blockIdx.x * 4 + (threadIdx.x >> 6);
    const int lane = threadIdx.x & 63;
    const float* row = se_raw + (size_t)n * 384;
    float v[6], s1 = 0.f, s2 = 0.f;
    #pragma unroll
    for (int q = 0; q < 6; ++q) {
        v[q] = row[lane + q * 64];
        s1 += v[q]; s2 += v[q] * v[q];
    }
    for (int mk = 1; mk < 64; mk <<= 1) {
        s1 += __shfl_xor(s1, mk, 64);
        s2 += __shfl_xor(s2, mk, 64);
    }
    float mu = s1 * (1.f / 384.f);
    float var = s2 * (1.f / 384.f) - mu * mu;
    float rs = rsqrtf(fmaxf(var, 0.f) + 1e-5f);
    unsigned short* orow = se0_bf + (size_t)n * 384;
    #pragma unroll
    for (int q = 0; q < 6; ++q) {
        int c = lane + q * 64;
        orow[c] = f2bf((v[q] - mu) * rs * ln_g[c] + ln_b[c]);
    }
}

// ------------------------------- K3: post-process --------------------------
// k/kp written bf16 (logit phase unpacks under MFMA cover); v/vp f32.
__global__ __launch_bounds__(256) void k_post(
    const float* __restrict__ lin,
    const float* __restrict__ r_rot, const float* __restrict__ r_trans,
    float* __restrict__ q_out, unsigned short* __restrict__ k_out,
    float* __restrict__ v_out, float* __restrict__ qp_out,
    unsigned short* __restrict__ kp_out, float* __restrict__ vp_out,
    float* __restrict__ k2_out)
{
    const int n0 = blockIdx.x * 8;
    const int t = threadIdx.x;
    __shared__ float kprot[8 * 144];

    for (int r = 0; r < 8; ++r) {
        const int n = n0 + r;
        const float* lrow = lin + (size_t)n * 1152;
        const float* rot = r_rot + (size_t)n * 45;        // frame 0
        for (int u = t; u < 1152; u += 256) {
            if (u < 192) {
                q_out[(size_t)n * 192 + u] = lrow[u];
            } else if (u < 576) {
                int l2 = u - 192, h = l2 >> 5, c = l2 & 31;
                float v = lrow[u];
                if (c < 16) k_out[(size_t)n * 192 + h * 16 + c] = f2bf(v);
                else        v_out[(size_t)n * 192 + h * 16 + (c - 16)] = v;
            } else {
                int y = u - 576;
                int pt = y / 3, i = y - pt * 3;
                float t0 = r_trans[(size_t)n * 15 + i];
                float v;
                if (pt < 48) {
                    v = rot[i*3+0] * lrow[576 + pt]
                      + rot[i*3+1] * lrow[576 + 48 + pt]
                      + rot[i*3+2] * lrow[576 + 96 + pt] + t0;
                    qp_out[(size_t)n * 144 + pt * 3 + i] = v;
                } else {
                    int pp = pt - 48;
                    v = rot[i*3+0] * lrow[720 + pp]
                      + rot[i*3+1] * lrow[720 + 144 + pp]
                      + rot[i*3+2] * lrow[720 + 288 + pp] + t0;
                    int h = pp / 12, pl = pp - h * 12;
                    if (pl < 4) {
                        kp_out[(size_t)n * 144 + (h * 4 + pl) * 3 + i] = f2bf(v);
                        kprot[r * 144 + (h * 4 + pl) * 3 + i] = v;
                    } else {
                        vp_out[(size_t)n * 288 + (h * 8 + (pl - 4)) * 3 + i] = v;
                    }
                }
            }
        }
    }
    __syncthreads();
    if (t < 96) {
        int r = t / 12, h = t - r * 12;
        float ss = 0.f;
        #pragma unroll
        for (int d = 0; d < 12; ++d) {
            float v = kprot[r * 144 + h * 12 + d];
            ss += v * v;
        }
        k2_out[(size_t)(n0 + r) * 12 + h] = ss;
    }
}

// ------------------------------- K4: fused attention (split-KV) ------------
// partial slot layout (stride 2048 floats):
//   [0,192)    o accumulator (raw, pre-division)
//   [192,480)  o_pt accumulator (raw, global frame)
//   [480,2016) o_pair accumulator [h][128] (raw)
//   [2016,2028) m per head ; [2028,2040) l per head
__global__ __launch_bounds__(256) void k_attn(
    const float* __restrict__ z, const float* __restrict__ mask,
    const float* __restrict__ head_w, const float* __restrict__ wb,
    const float* __restrict__ bb,
    const float* __restrict__ q_ws, const float* __restrict__ qp_ws,
    const float* __restrict__ k2_ws,
    const unsigned short* __restrict__ k_bf, const float* __restrict__ v_f,
    const unsigned short* __restrict__ kp_bf, const float* __restrict__ vp_f,
    float* __restrict__ parts)
{
    const int i = blockIdx.x >> 1;
    const int half = blockIdx.x & 1;
    const int t = threadIdx.x;
    const int lane = t & 63, wv = t >> 6;
    const int quad = lane >> 4, lcol = lane & 15;

    __shared__ short zb[64 * 136];             // swizzled bf16 z tile (17.4 KB)
    __shared__ float L[64 * 17];               // logits [jl][h]; reused as vbuf
    __shared__ float Pt[16 * 68];              // softmax weights [h][jl]
    __shared__ float qs[192], qps[144];
    __shared__ float ulra[384];                // this half's mask column
    __shared__ float m_s[16], l_s[16], alph_s[16];

    const float c_qk = 0.14433756729740643f;   // 1/sqrt(3*CH)
    const float c_b  = 0.57735026918962576f;   // 1/sqrt(3)

    if (t < 192) qs[t]  = q_ws[(size_t)i * 192 + t];
    if (t < 144) qps[t] = qp_ws[(size_t)i * 144 + t];
    if (t >= 192 && t < 208) { int u = t - 192; m_s[u] = -1e30f; l_s[u] = 0.f; alph_s[u] = 1.f; }
    for (int x = t; x < 384; x += 256) ulra[x] = mask[(size_t)(half * 384 + x) * 5];
    for (int x = t; x < 4 * 68; x += 256) Pt[12 * 68 + x] = 0.f;   // pad heads
    const float ulr_i = mask[(size_t)i * 5];

    // wb B-fragments, resident in registers
    s16x8 wbf[4];
    #pragma unroll
    for (int kb = 0; kb < 4; ++kb) {
        #pragma unroll
        for (int j = 0; j < 8; ++j) {
            int c = kb * 32 + quad * 8 + j;
            wbf[kb][j] = (lcol < 12) ? (short)f2bf(wb[(size_t)lcol * 128 + c]) : (short)0;
        }
    }
    __syncthreads();

    // per-thread hoisted q/qp/consts for the logit phase (head = lcol, clamped)
    const int hh = (lcol < 12) ? lcol : 11;
    f32x4 qv[4], qpv[3];
    float q2_r = 0.f;
    #pragma unroll
    for (int m = 0; m < 4; ++m) qv[m] = *(const f32x4*)&qs[hh * 16 + m * 4];
    #pragma unroll
    for (int m = 0; m < 3; ++m) {
        qpv[m] = *(const f32x4*)&qps[hh * 12 + m * 4];
        #pragma unroll
        for (int e = 0; e < 4; ++e) q2_r += qpv[m][e] * qpv[m][e];
    }
    float xh = head_w[hh];
    const float cpt_r = -0.5f * logf(1.f + __expf(xh)) * 0.13608276348795434f;
    const float cbb_r = c_b * bb[hh];

    f32x4 acc_op[2] = { {0.f,0.f,0.f,0.f}, {0.f,0.f,0.f,0.f} };  // o_pair (MFMA C)
    f32x4 acc_s = {0.f,0.f,0.f,0.f};                              // o / o_pt partial

    // value-phase roles: 240 threads x 32 j (two halves)
    int vu = -1, vhalf = 0;
    if (t < 120) { vu = t; vhalf = 0; }
    else if (t >= 128 && t < 248) { vu = t - 128; vhalf = 1; }
    int vrole = -1; const float* vsrc = nullptr; int vstride = 0, voff = 0;
    if (vu >= 0) {
        if (vu < 48) { vrole = vu >> 2;       vsrc = v_f;  vstride = 192; voff = vu * 4; }
        else         { vrole = (vu - 48) / 6; vsrc = vp_f; vstride = 288; voff = (vu - 48) * 4; }
    }

    // prefetch z tile 0 of this half into registers
    const float* zbase = z + (size_t)i * 98304 + (size_t)half * 49152;
    f32x4 zr[8];
    #pragma unroll
    for (int sx = 0; sx < 8; ++sx)
        zr[sx] = *(const f32x4*)(zbase + (size_t)(t + sx * 256) * 4);

    const int jlb = wv * 16 + quad * 4;
    const int zrow = wv * 16 + lcol;
    const int sigm = (zrow >> 3) & 3;

    for (int tt = 0; tt < 6; ++tt) {
        const int j0 = half * 384 + tt * 64;   // global j base
        const int jloc0 = tt * 64;             // local (half) j base
        __syncthreads();   // A: previous tile's zb/Pt readers done

        // ---- store prefetched z tile (swizzled 16B chunks) ----
        #pragma unroll
        for (int sx = 0; sx < 8; ++sx) {
            int idx = t + sx * 256;
            int jl = idx >> 5, cq = idx & 31;
            int ch = (cq >> 1) ^ ((jl >> 3) & 3);
            uint2 pk;
            pk.x = packbf2(zr[sx][0], zr[sx][1]);
            pk.y = packbf2(zr[sx][2], zr[sx][3]);
            *(uint2*)&zb[jl * 136 + ch * 8 + (cq & 1) * 4] = pk;
        }
        __syncthreads();   // B

        // ---- issue next z tile loads (overlap with whole tile compute) ----
        if (tt < 5) {
            const float* znext = zbase + (size_t)(tt + 1) * 8192;
            #pragma unroll
            for (int sx = 0; sx < 8; ++sx)
                zr[sx] = *(const f32x4*)(znext + (size_t)(t + sx * 256) * 4);
        }
        // ---- issue k/kp/K2 loads for this thread's 4 j-rows ----
        uint4 ka[4], kb4[4]; uint2 p0[4], p1[4], p2[4]; float K2r[4];
        #pragma unroll
        for (int r = 0; r < 4; ++r) {
            int jr = j0 + jlb + r;
            const unsigned short* kr = k_bf + (size_t)jr * 192 + hh * 16;
            ka[r]  = *(const uint4*)kr;
            kb4[r] = *(const uint4*)(kr + 8);
            const unsigned short* pr = kp_bf + (size_t)jr * 144 + hh * 12;
            p0[r] = *(const uint2*)pr;
            p1[r] = *(const uint2*)(pr + 4);
            p2[r] = *(const uint2*)(pr + 8);
            K2r[r] = k2_ws[(size_t)jr * 12 + hh];
        }

        // ---- bias via MFMA (covers the L2 latency of the loads above) ----
        f32x4 d = {0.f, 0.f, 0.f, 0.f};
        #pragma unroll
        for (int kb = 0; kb < 4; ++kb) {
            s16x8 a = *(const s16x8*)&zb[zrow * 136 + ((kb * 4 + quad) ^ sigm) * 8];
            d = __builtin_amdgcn_mfma_f32_16x16x32_bf16(a, wbf[kb], d, 0, 0, 0);
        }

        // ---- logits: thread owns (jl = jlb+r, h = lcol) ----
        if (lcol < 12) {
            #pragma unroll
            for (int r = 0; r < 4; ++r) {
                int jl = jlb + r;
                const unsigned* kwa = (const unsigned*)&ka[r];
                const unsigned* kwb = (const unsigned*)&kb4[r];
                float qk = 0.f;
                #pragma unroll
                for (int m = 0; m < 4; ++m) {
                    qk += qv[m >> 1][(m & 1) * 2 + 0] * bf2f((unsigned short)(kwa[m] & 0xffffu));
                    qk += qv[m >> 1][(m & 1) * 2 + 1] * bf2f((unsigned short)(kwa[m] >> 16));
                }
                #pragma unroll
                for (int m = 0; m < 4; ++m) {
                    qk += qv[2 + (m >> 1)][(m & 1) * 2 + 0] * bf2f((unsigned short)(kwb[m] & 0xffffu));
                    qk += qv[2 + (m >> 1)][(m & 1) * 2 + 1] * bf2f((unsigned short)(kwb[m] >> 16));
                }
                float dp = 0.f;
                dp += qpv[0][0] * bf2f((unsigned short)(p0[r].x & 0xffffu));
                dp += qpv[0][1] * bf2f((unsigned short)(p0[r].x >> 16));
                dp += qpv[0][2] * bf2f((unsigned short)(p0[r].y & 0xffffu));
                dp += qpv[0][3] * bf2f((unsigned short)(p0[r].y >> 16));
                dp += qpv[1][0] * bf2f((unsigned short)(p1[r].x & 0xffffu));
                dp += qpv[1][1] * bf2f((unsigned short)(p1[r].x >> 16));
                dp += qpv[1][2] * bf2f((unsigned short)(p1[r].y & 0xffffu));
                dp += qpv[1][3] * bf2f((unsigned short)(p1[r].y >> 16));
                dp += qpv[2][0] * bf2f((unsigned short)(p2[r].x & 0xffffu));
                dp += qpv[2][1] * bf2f((unsigned short)(p2[r].x >> 16));
                dp += qpv[2][2] * bf2f((unsigned short)(p2[r].y & 0xffffu));
                dp += qpv[2][3] * bf2f((unsigned short)(p2[r].y >> 16));
                float ptt = cpt_r * (q2_r + K2r[r] - 2.f * dp);
                float lg = c_qk * qk + ptt + 1e5f * (ulr_i * ulra[jloc0 + jl] - 1.f)
                         + c_b * d[r] + cbb_r;
                L[jl * 17 + lcol] = lg;
            }
        }
        __syncthreads();   // C

        // ---- online softmax update (16 lanes per head) ----
        if (t < 192) {
            int h = t >> 4, u = t & 15;
            float v0 = L[(u * 4 + 0) * 17 + h];
            float v1 = L[(u * 4 + 1) * 17 + h];
            float v2 = L[(u * 4 + 2) * 17 + h];
            float v3 = L[(u * 4 + 3) * 17 + h];
            float mx = fmaxf(fmaxf(v0, v1), fmaxf(v2, v3));
            for (int mk = 1; mk < 16; mk <<= 1) mx = fmaxf(mx, __shfl_xor(mx, mk, 16));
            float mold = m_s[h];
            float mnew = fmaxf(mold, mx);
            float w0 = __expf(v0 - mnew), w1 = __expf(v1 - mnew);
            float w2 = __expf(v2 - mnew), w3 = __expf(v3 - mnew);
            Pt[h * 68 + u * 4 + 0] = w0;
            Pt[h * 68 + u * 4 + 1] = w1;
            Pt[h * 68 + u * 4 + 2] = w2;
            Pt[h * 68 + u * 4 + 3] = w3;
            float sm = w0 + w1 + w2 + w3;
            for (int mk = 1; mk < 16; mk <<= 1) sm += __shfl_xor(sm, mk, 16);
            if (u == 0) {
                float al = __expf(mold - mnew);
                m_s[h] = mnew; alph_s[h] = al;
                l_s[h] = l_s[h] * al + sm;
            }
        }
        __syncthreads();   // D

        // ---- o_pair MFMA: D[h][c] += P(16x64) @ z(64x128) ----
        {
            float al[4];
            #pragma unroll
            for (int r = 0; r < 4; ++r) al[r] = alph_s[quad * 4 + r];
            #pragma unroll
            for (int nt = 0; nt < 2; ++nt)
                #pragma unroll
                for (int r = 0; r < 4; ++r) acc_op[nt][r] *= al[r];
            #pragma unroll
            for (int kb = 0; kb < 2; ++kb) {
                f32x4 pa = *(const f32x4*)&Pt[lcol * 68 + kb * 32 + quad * 8];
                f32x4 pb = *(const f32x4*)&Pt[lcol * 68 + kb * 32 + quad * 8 + 4];
                union { s16x8 v; unsigned u[4]; } af;
                af.u[0] = packbf2(pa[0], pa[1]);
                af.u[1] = packbf2(pa[2], pa[3]);
                af.u[2] = packbf2(pb[0], pb[1]);
                af.u[3] = packbf2(pb[2], pb[3]);
                #pragma unroll
                for (int nt = 0; nt < 2; ++nt) {
                    int c = wv * 32 + nt * 16 + lcol;
                    int csw = ((c >> 3) ^ quad) * 8 + (c & 7);
                    s16x8 bfg;
                    #pragma unroll
                    for (int j = 0; j < 8; ++j)
                        bfg[j] = zb[(kb * 32 + quad * 8 + j) * 136 + csw];
                    acc_op[nt] = __builtin_amdgcn_mfma_f32_16x16x32_bf16(af.v, bfg, acc_op[nt], 0, 0, 0);
                }
            }
        }
        // ---- scalar o / o_pt (f32 v, v_pts from L2: no unpack VALU) ----
        if (vu >= 0) {
            float alpha = alph_s[vrole];
            f32x4 a = acc_s;
            a[0] *= alpha; a[1] *= alpha; a[2] *= alpha; a[3] *= alpha;
            const float* prow = &Pt[vrole * 68 + vhalf * 32];
            const float* src = vsrc + (size_t)(j0 + vhalf * 32) * vstride + voff;
            #pragma unroll 4
            for (int jj = 0; jj < 32; jj += 4) {
                f32x4 p = *(const f32x4*)(prow + jj);
                #pragma unroll
                for (int m = 0; m < 4; ++m) {
                    f32x4 w = *(const f32x4*)(src + (size_t)(jj + m) * vstride);
                    float pm = p[m];
                    a[0] += pm * w[0];
                    a[1] += pm * w[1];
                    a[2] += pm * w[2];
                    a[3] += pm * w[3];
                }
            }
            acc_s = a;
        }
    }

    // ------------------------------ epilogue: write raw partials -----------
    __syncthreads();
    float* pr = parts + (size_t)(i * 2 + half) * 2048;
    if (t < 12) { pr[2016 + t] = m_s[t]; pr[2028 + t] = l_s[t]; }
    float* vbuf = L;    // safe: no more L readers
    if (vu >= 0) {
        #pragma unroll
        for (int m = 0; m < 4; ++m) vbuf[(vu * 2 + vhalf) * 4 + m] = acc_s[m];
    }
    __syncthreads();
    if (t < 120) {   // combine value halves (no 1/l here)
        float f[4];
        #pragma unroll
        for (int m = 0; m < 4; ++m)
            f[m] = vbuf[(t * 2) * 4 + m] + vbuf[(t * 2 + 1) * 4 + m];
        if (t < 48) {
            #pragma unroll
            for (int m = 0; m < 4; ++m) pr[t * 4 + m] = f[m];
        } else {
            int e0 = (t - 48) * 4;
            pr[192 + e0 + 0] = f[0]; pr[192 + e0 + 1] = f[1];
            pr[192 + e0 + 2] = f[2]; pr[192 + e0 + 3] = f[3];
        }
    }
    {
        #pragma unroll
        for (int nt = 0; nt < 2; ++nt)
            #pragma unroll
            for (int r = 0; r < 4; ++r) {
                int h = quad * 4 + r;
                if (h < 12)
                    pr[480 + h * 128 + wv * 32 + nt * 16 + lcol] = acc_op[nt][r];
            }
    }
}

// ------------------------------- K6: merge halves + frame inversion --------
__global__ __launch_bounds__(256) void k_merge(
    const float* __restrict__ parts,
    const float* __restrict__ r_rot, const float* __restrict__ r_trans,
    unsigned short* __restrict__ cat)
{
    const int i = blockIdx.x;
    const int t = threadIdx.x;
    const float* p1 = parts + (size_t)(i * 2 + 0) * 2048;
    const float* p2 = parts + (size_t)(i * 2 + 1) * 2048;
    __shared__ float w1s[12], w2s[12], lis[12];
    if (t < 12) {
        float m1 = p1[2016 + t], l1 = p1[2028 + t];
        float m2 = p2[2016 + t], l2 = p2[2028 + t];
        float m = fmaxf(m1, m2);
        float w1 = __expf(m1 - m), w2 = __expf(m2 - m);
        w1s[t] = w1; w2s[t] = w2;
        lis[t] = 1.f / (w1 * l1 + w2 * l2);
    }
    __syncthreads();
    unsigned short* crow = cat + (size_t)i * 2112;
    if (t < 192) {   // o
        int h = t >> 4;
        crow[t] = f2bf((w1s[h] * p1[t] + w2s[h] * p2[t]) * lis[h]);
    }
    #pragma unroll
    for (int k = 0; k < 6; ++k) {   // o_pair
        int c = t + k * 256;
        int h = c >> 7;
        crow[576 + c] = f2bf((w1s[h] * p1[480 + c] + w2s[h] * p2[480 + c]) * lis[h]);
    }
    if (t < 96) {    // o_pt: merge, invert frame 0, norm
        int hp = t, h = hp >> 3;
        const float* rot = r_rot + (size_t)i * 45;
        float o0 = (w1s[h] * p1[192 + hp * 3 + 0] + w2s[h] * p2[192 + hp * 3 + 0]) * lis[h];
        float o1 = (w1s[h] * p1[192 + hp * 3 + 1] + w2s[h] * p2[192 + hp * 3 + 1]) * lis[h];
        float o2 = (w1s[h] * p1[192 + hp * 3 + 2] + w2s[h] * p2[192 + hp * 3 + 2]) * lis[h];
        float d0 = o0 - r_trans[(size_t)i * 15 + 0];
        float d1 = o1 - r_trans[(size_t)i * 15 + 1];
        float d2 = o2 - r_trans[(size_t)i * 15 + 2];
        float f0 = rot[0] * d0 + rot[3] * d1 + rot[6] * d2;
        float f1 = rot[1] * d0 + rot[4] * d1 + rot[7] * d2;
        float f2 = rot[2] * d0 + rot[5] * d1 + rot[8] * d2;
        crow[192 + hp] = f2bf(f0);
        crow[288 + hp] = f2bf(f1);
        crow[384 + hp] = f2bf(f2);
        crow[480 + hp] = f2bf(sqrtf(f0 * f0 + f1 * f1 + f2 * f2 + 1e-8f));
    }
}

// ------------------------------- K5: reduce split-K parts + bias -----------
__global__ __launch_bounds__(256) void k_out_red(
    const float* __restrict__ parts, const float* __restrict__ bout,
    float* __restrict__ out)
{
    const int x = blockIdx.x * 256 + threadIdx.x;   // < 294912
    float s = bout[x % 384];
    #pragma unroll
    for (int p = 0; p < 6; ++p) s += parts[(size_t)p * 294912 + x];
    out[x] = s;
}

// ------------------------------- launch ------------------------------------
extern "C" void kernel_launch(void* const* d_in, const int* in_sizes, int n_in,
                              void* d_out, int out_size, void* d_ws, size_t ws_size,
                              hipStream_t stream)
{
    const float* s       = (const float*)d_in[0];
    const float* z       = (const float*)d_in[1];
    const float* r_rot   = (const float*)d_in[2];
    const float* r_trans = (const float*)d_in[3];
    const float* mask    = (const float*)d_in[4];
    const float* wq      = (const float*)d_in[5];
    const float* bq      = (const float*)d_in[6];
    const float* wkv     = (const float*)d_in[7];
    const float* bkv     = (const float*)d_in[8];
    const float* wqp     = (const float*)d_in[9];
    const float* bqp     = (const float*)d_in[10];
    const float* wkvp    = (const float*)d_in[11];
    const float* bkvp    = (const float*)d_in[12];
    const float* wb      = (const float*)d_in[13];
    const float* bb      = (const float*)d_in[14];
    const float* head_w  = (const float*)d_in[15];
    const float* wout    = (const float*)d_in[16];
    const float* bout    = (const float*)d_in[17];
    const float* wexp    = (const float*)d_in[18];
    const float* bexp    = (const float*)d_in[19];
    const float* ln_g    = (const float*)d_in[20];
    const float* ln_b    = (const float*)d_in[21];
    // d_in[22]=ww, d_in[23]=bw unused: softmax over size-1 axis == 1.0

    float* wsf = (float*)d_ws;
    float* se_raw = wsf;                  // 294912
    float* lin    = wsf + 294912;         // 884736
    float* qf     = wsf + 1179648;        // 147456
    float* qpf    = wsf + 1327104;        // 110592
    float* k2w    = wsf + 1437696;        // 9216
    float* bcat   = wsf + 1446912;        // 1152
    float* gparts = wsf + 1448064;        // 1769472 (6 x 294912)
    float* vf     = wsf + 3217536;        // 147456
    float* vpf    = wsf + 3364992;        // 221184
    unsigned short* ub = (unsigned short*)(wsf + 3586176);
    unsigned short* s_bf   = ub;              // 294912
    unsigned short* we_bf  = ub + 294912;     // 147456
    unsigned short* wc_bf  = ub + 442368;     // 442368
    unsigned short* wo_bf  = ub + 884736;     // 811008
    unsigned short* se0_bf = ub + 1695744;    // 294912
    unsigned short* kbf    = ub + 1990656;    // 147456
    unsigned short* kpbf   = ub + 2138112;    // 110592
    unsigned short* cat_bf = ub + 2248704;    // 1622016
    float* pa_ws  = wsf + 5521536;        // 3145728 (1536 x 2048 attn partials)
    float* out = (float*)d_out;

    k_prep<<<6629, 256, 0, stream>>>(s, wexp, wq, wkv, wqp, wkvp, wout,
                                     bq, bkv, bqp, bkvp,
                                     s_bf, we_bf, wc_bf, wo_bf, bcat);
    k_mm<<<dim3(12, 6, 1), 256, 0, stream>>>(s_bf, 384, we_bf, 384,
                                             se_raw, 384, bexp, 12, 0);
    k_ln<<<192, 256, 0, stream>>>(se_raw, ln_g, ln_b, se0_bf);
    k_mm<<<dim3(12, 18, 1), 256, 0, stream>>>(se0_bf, 384, wc_bf, 384,
                                              lin, 1152, bcat, 12, 0);
    k_post<<<96, 256, 0, stream>>>(lin, r_rot, r_trans,
                                   qf, kbf, vf, qpf, kpbf, vpf, k2w);
    k_attn<<<1536, 256, 0, stream>>>(z, mask, head_w, wb, bb,
                                     qf, qpf, k2w, kbf, vf, kpbf, vpf, pa_ws);
    k_merge<<<768, 256, 0, stream>>>(pa_ws, r_rot, r_trans, cat_bf);
    k_mm<<<dim3(12, 6, 6), 256, 0, stream>>>(cat_bf, 2112, wo_bf, 2112,
                                             gparts, 384, nullptr, 11, 294912);
    k_out_red<<<1152, 256, 0, stream>>>(gparts, bout, out);
}